// Round 19
// baseline (81.512 us; speedup 1.0000x reference)
//
#include <hip/hip_runtime.h>
#include <type_traits>

#define NQ 10
#define N_DEPTH 5
#define DIM 1024
#define BATCH 16384
#define IN_DIM 784
#define NGATES 50
#define KALLOC 832    // fp8 row length (13*64); cols >=784 zero
#define NT 13         // K-tiles of 64
#define NSLOT 768     // kept complex amp slots (p0|p1), group-blocked
#define NB 12         // gemm n-blocks (1536 fp8 rows / 128)

typedef float f32x2 __attribute__((ext_vector_type(2)));
typedef float f32x4 __attribute__((ext_vector_type(4)));
typedef unsigned u32x4 __attribute__((ext_vector_type(4)));
typedef long lx2 __attribute__((ext_vector_type(2)));

// ---------------------------------------------------------------------------
// Compile-time mask tables: CNOTs absorbed into GF(2)-linear index transform.
// ---------------------------------------------------------------------------
struct MaskTab {
  unsigned v[NGATES];
  unsigned p[NGATES];
  unsigned vz0, vz1;
};

constexpr MaskTab make_masks() {
  MaskTab t{};
  unsigned v[NQ], p[NQ];
  for (int i = 0; i < NQ; ++i) { v[i] = 1u << (9 - i); p[i] = 1u << (9 - i); }
  for (int d = 0; d < N_DEPTH; ++d) {
    for (int i = 0; i < NQ; ++i) {
      int c = i, tt = (i + 1) % NQ;
      v[tt] ^= v[c];
      p[c]  ^= p[tt];
    }
    for (int i = 0; i < NQ; ++i) {
      t.v[d * NQ + i] = v[i];
      t.p[d * NQ + i] = p[i];
    }
  }
  t.vz0 = v[0];
  t.vz1 = v[1];
  return t;
}

constexpr MaskTab MT = make_masks();
__constant__ MaskTab d_MT = make_masks();

// Permutation: state m -> slot. Groups of 256 complex slots:
//   A [0,256): p0=1,p1=0   B [256,512): p0=0,p1=1   C [512,768): p0=1,p1=1
// z0 = n2 - 2(SA+SC), z1 = n2 - 2(SB+SC); n2 = |x|^2 exact (unitarity).
struct PermTab { short slot[DIM]; };
constexpr PermTab make_perm() {
  PermTab t{};
  int a = 0, b = 256, c = 512;
  for (int m = 0; m < DIM; ++m) {
    const int p0 = __builtin_popcount((unsigned)m & MT.vz0) & 1;
    const int p1 = __builtin_popcount((unsigned)m & MT.vz1) & 1;
    if (p0 && !p1)      t.slot[m] = (short)a++;
    else if (!p0 && p1) t.slot[m] = (short)b++;
    else if (p0 && p1)  t.slot[m] = (short)c++;
    else                t.slot[m] = -1;
  }
  return t;
}
__constant__ PermTab d_PT = make_perm();

// d = co*o + cp*q (complex), packed (re,im); 4 VOP3P instrs (verified r2-r18).
__device__ __forceinline__ f32x2 ampfma(f32x2 o, f32x2 q, f32x2 co, f32x2 cp) {
  f32x2 d;
  asm("v_pk_mul_f32 %0, %2, %1 op_sel:[0,0] op_sel_hi:[0,1]\n\t"
      "v_pk_fma_f32 %0, %2, %1, %0 op_sel:[1,1,0] op_sel_hi:[1,0,1] neg_lo:[1,0,0]\n\t"
      "v_pk_fma_f32 %0, %3, %4, %0 op_sel:[0,0,0] op_sel_hi:[0,1,1]\n\t"
      "v_pk_fma_f32 %0, %3, %4, %0 op_sel:[1,1,0] op_sel_hi:[1,0,1] neg_lo:[1,0,0]"
      : "=&v"(d)
      : "v"(o), "v"(co), "v"(cp), "v"(q));
  return d;
}

__device__ __forceinline__ float fxor(float x, unsigned m) {
  return __uint_as_float(__float_as_uint(x) ^ m);
}

// pack 4 f32 -> 4 fp8 e4m3 bytes (OCP) in a u32
__device__ __forceinline__ unsigned pk4_fp8(float a, float b, float c, float d) {
  int v = __builtin_amdgcn_cvt_pk_fp8_f32(a, b, 0, false);
  v = __builtin_amdgcn_cvt_pk_fp8_f32(c, d, v, true);
  return (unsigned)v;
}

__device__ __forceinline__ void gll16(const void* g, void* l) {
  __builtin_amdgcn_global_load_lds(
      (const __attribute__((address_space(1))) void*)g,
      (__attribute__((address_space(3))) void*)l, 16, 0, 0);
}

#define XSCALE 32.0f
#define WSCALE 16.0f
#define SINV   (1.0f / 262144.0f)   // 1/(32*16)^2

// Column permutation baked into fp8 rows: within each 64B k-group, the 8B
// chunk kb (0..7) lives at byte (kb&3)*16 + (kb>>2)*8.  =>  16B physical
// block p of a group holds chunks {p, p+4}; a lane's MFMA frag-pair
// (kb=kc, kb=kc+4) is ONE aligned 16B read.

// ---------------------------------------------------------------------------
// K0+K1 merged. build_w blocks FIRST:
//   blocks [0, 832):     basis columns e_j -> W2T[1536 rows][832] fp8,
//                        scatter-written at permuted column positions
//   blocks [832, 2880):  xcvt 8 rows/block: X f32 -> Xf8 (x*32, permuted
//                        columns) + xn2 = |x|^2
// ---------------------------------------------------------------------------
__global__ __launch_bounds__(256) void prep(const float* __restrict__ X,
                                            char* __restrict__ Xf8,
                                            float* __restrict__ xn2,
                                            const float* __restrict__ w,
                                            char* __restrict__ W2T) {
  __shared__ f32x4 UL4[NGATES];
  __shared__ f32x2 S0[DIM];
  __shared__ f32x2 S1[DIM];

  const int tid = threadIdx.x;

  if (blockIdx.x >= 832) {
    // ---- xcvt + row-norm: 8 rows/block, 32 lanes/row; 52 output blocks ----
    const int row = (blockIdx.x - 832) * 8 + (tid >> 5);
    const int l32 = tid & 31;
    const float* src = X + (size_t)row * IN_DIM;
    char* dst = Xf8 + (size_t)row * KALLOC;
    float ssq = 0.0f;
    for (int b = l32; b < 52; b += 32) {
      const int g = b >> 2, wq = b & 3;
      const int k1 = g * 64 + wq * 8;           // chunk kb=wq
      const int k2 = k1 + 32;                   // chunk kb=wq+4
      u32x4 out = u32x4{0, 0, 0, 0};
      if (k1 < IN_DIM) {                        // k1+7 <= 783 whenever k1<784
        f32x4 v0 = *(const f32x4*)(src + k1);
        f32x4 v1 = *(const f32x4*)(src + k1 + 4);
        ssq += v0.x * v0.x + v0.y * v0.y + v0.z * v0.z + v0.w * v0.w +
               v1.x * v1.x + v1.y * v1.y + v1.z * v1.z + v1.w * v1.w;
        out.x = pk4_fp8(v0.x * XSCALE, v0.y * XSCALE, v0.z * XSCALE, v0.w * XSCALE);
        out.y = pk4_fp8(v1.x * XSCALE, v1.y * XSCALE, v1.z * XSCALE, v1.w * XSCALE);
      }
      if (k2 < IN_DIM) {
        f32x4 v2 = *(const f32x4*)(src + k2);
        f32x4 v3 = *(const f32x4*)(src + k2 + 4);
        ssq += v2.x * v2.x + v2.y * v2.y + v2.z * v2.z + v2.w * v2.w +
               v3.x * v3.x + v3.y * v3.y + v3.z * v3.z + v3.w * v3.w;
        out.z = pk4_fp8(v2.x * XSCALE, v2.y * XSCALE, v2.z * XSCALE, v2.w * XSCALE);
        out.w = pk4_fp8(v3.x * XSCALE, v3.y * XSCALE, v3.z * XSCALE, v3.w * XSCALE);
      }
      *(u32x4*)(dst + b * 16) = out;
    }
#pragma unroll
    for (int off = 1; off < 32; off <<= 1) ssq += __shfl_xor(ssq, off);
    if (l32 == 0) xn2[row] = ssq;
    return;
  }

  // ---- build_w (gate loop verified r6-r18) ----
  if (tid < NGATES) {
    // qml.Rot(phi, theta, omega) = RZ(omega) RY(theta) RZ(phi)
    float phi = w[tid * 3 + 0], th = w[tid * 3 + 1], om = w[tid * 3 + 2];
    float ct = cosf(th * 0.5f), st = sinf(th * 0.5f);
    float aa = (phi + om) * 0.5f, bb = (phi - om) * 0.5f;
    float cA = cosf(aa), sA = sinf(aa), cB = cosf(bb), sB = sinf(bb);
    // u00 = e^{-ia} c ; u01 = -e^{+ib} s  (u11 = conj(u00), u10 = -conj(u01))
    UL4[tid] = f32x4{ ct * cA, -ct * sA, -st * cB, -st * sB };
  }

  const int j = blockIdx.x;                     // 0..831
  // permuted position of column j within each row
  const int jp = (j >> 6) * 64 + (((j >> 3) & 3) << 4) + (((j >> 5) & 1) << 3)
                 + (j & 7);

  if (j >= IN_DIM) {                            // zero pad columns j>=784
#pragma unroll
    for (int k = 0; k < 3; ++k) {
      const int s = tid + k * 256;              // slot 0..767
      W2T[(size_t)(2 * s) * KALLOC + jp] = 0;
      W2T[(size_t)(2 * s + 1) * KALLOC + jp] = 0;
    }
    return;
  }

#pragma unroll
  for (int k = 0; k < 4; ++k) {
    const int m = tid + k * 256;
    S0[m] = f32x2{(m == j) ? 1.0f : 0.0f, 0.0f};
  }
  __syncthreads();

  for (int g = 0; g < NGATES; ++g) {
    const f32x2* src = (g & 1) ? S1 : S0;
    f32x2* dst = (g & 1) ? S0 : S1;
    const f32x4 A = UL4[g];
    const unsigned v = d_MT.v[g];
    const unsigned p = d_MT.p[g];
#pragma unroll
    for (int k = 0; k < 4; ++k) {
      const int m = tid + k * 256;
      f32x2 o = src[m];
      f32x2 q = src[m ^ (int)p];
      const unsigned sg = (unsigned)(__popc((int)((unsigned)m & v)) & 1) << 31;
      const f32x2 co = {A.x, fxor(A.y, sg)};
      const f32x2 cp = {fxor(A.z, sg), A.w};
      dst[m] = ampfma(o, q, co, cp);
    }
    __syncthreads();
  }

  const f32x2* fin = S0;   // 50 gates (even) -> final state back in S0
#pragma unroll
  for (int k = 0; k < 4; ++k) {
    const int m = tid + k * 256;
    const int s = d_PT.slot[m];
    f32x2 a = fin[m];
    if (s >= 0) {
      const unsigned pk = pk4_fp8(a.x * WSCALE, a.y * WSCALE, 0.0f, 0.0f);
      W2T[(size_t)(2 * s) * KALLOC + jp] = (char)(pk & 0xffu);
      W2T[(size_t)(2 * s + 1) * KALLOC + jp] = (char)((pk >> 8) & 0xffu);
    }
  }
}

// ---------------------------------------------------------------------------
// K3 v17: r18 fp8 gemm with b128 frag-pair reads (permuted column layout).
// 768 blocks (64mb x 12nb), LDS 2 x (A 16KB + B 8KB) = 48KB -> 3 blocks/CU.
// 8 waves 2M x 4N, wave tile 128x32, acc[8][2]. BK=64 = one 64B k-group per
// tile, one barrier/tile. Stage swizzle chunk' = c ^ sw(row) (r17/r18),
// frag-pair = ONE ds_read_b128 at physical block kc ^ sw(row): low 8B = kb
// kc, high 8B = kb kc+4. 10 b128 reads/wave-tile (was 20 b64).
// ---------------------------------------------------------------------------
__global__ __launch_bounds__(512) void gemm_fused(const char* __restrict__ Xf8,
                                                  const char* __restrict__ W2T,
                                                  float* __restrict__ accb) {
  __shared__ u32x4 lds4[3072];   // 48 KB
  char* lds = (char*)lds4;

  const int tid = threadIdx.x;
  const int orig = blockIdx.x;                    // 768 blocks
  const int bx = (orig & 7) * 96 + (orig >> 3);   // XCD-chunked (768%8==0)
  const int mb = bx / NB, nb = bx % NB;
  const int m0 = mb * 256, n0 = nb * 128;
  const int lane = tid & 63, wv = tid >> 6;
  const int wm = wv >> 2, wn = wv & 3;

  // stage lane geometry (verified r17/r18): unit g = 1KB = 16 rows x 64B.
  // lane l -> row_local l>>2, chunk' = l&3; source chunk c = (l&3)^sw(l>>2),
  // sw(r) = (r&3)^((r>>2)&3)  ->  phys chunk' = c ^ sw(row).
  const int rl = lane >> 2;
  const int csrc = (lane & 3) ^ (rl & 3) ^ ((rl >> 2) & 3);

  auto stage = [&](int t) {
    char* Ab = lds + (t & 1) * 24576;
    char* Bb = Ab + 16384;
    const int col = t * 64 + csrc * 16;
#pragma unroll
    for (int i = 0; i < 2; ++i) {                 // A: 2 units/wave (16 total)
      const int g = wv * 2 + i;
      const int row = g * 16 + rl;
      gll16(Xf8 + (size_t)(m0 + row) * KALLOC + col, Ab + g * 1024);
    }
    {                                             // B: 1 unit/wave (8 total)
      const int row = wv * 16 + rl;
      gll16(W2T + (size_t)(n0 + row) * KALLOC + col, Bb + wv * 1024);
    }
  };

  stage(0);
  asm volatile("s_waitcnt vmcnt(0)" ::: "memory");
  __builtin_amdgcn_s_barrier();

  f32x4 acc[8][2];
#pragma unroll
  for (int fm = 0; fm < 8; ++fm)
#pragma unroll
    for (int fn = 0; fn < 2; ++fn) acc[fm][fn] = f32x4{0, 0, 0, 0};

  const int kc = lane >> 4;                       // k-chunk pair index 0..3

  for (int t = 0; t < NT; ++t) {
    const char* Ab = lds + (t & 1) * 24576;
    const char* Bb = Ab + 16384;

    long af0[8], bf0[2], af1[8], bf1[2];
#pragma unroll
    for (int f = 0; f < 8; ++f) {
      const int ar = wm * 128 + f * 16 + (lane & 15);
      const int sw = (ar & 3) ^ ((ar >> 2) & 3);
      lx2 va = *(const lx2*)(Ab + ar * 64 + ((kc ^ sw) * 16));
      af0[f] = va.x;
      af1[f] = va.y;
    }
#pragma unroll
    for (int f = 0; f < 2; ++f) {
      const int br = wn * 32 + f * 16 + (lane & 15);
      const int sw = (br & 3) ^ ((br >> 2) & 3);
      lx2 vb = *(const lx2*)(Bb + br * 64 + ((kc ^ sw) * 16));
      bf0[f] = vb.x;
      bf1[f] = vb.y;
    }
    if (t < NT - 1) stage(t + 1);                 // -> other buffer (safe)

    __builtin_amdgcn_s_setprio(1);
#pragma unroll
    for (int fm = 0; fm < 8; ++fm)
#pragma unroll
      for (int fn = 0; fn < 2; ++fn)
        acc[fm][fn] = __builtin_amdgcn_mfma_f32_16x16x32_fp8_fp8(
            af0[fm], bf0[fn], acc[fm][fn], 0, 0, 0);
    __builtin_amdgcn_s_setprio(0);

    __builtin_amdgcn_s_setprio(1);
#pragma unroll
    for (int fm = 0; fm < 8; ++fm)
#pragma unroll
      for (int fn = 0; fn < 2; ++fn)
        acc[fm][fn] = __builtin_amdgcn_mfma_f32_16x16x32_fp8_fp8(
            af1[fm], bf1[fn], acc[fm][fn], 0, 0, 0);
    __builtin_amdgcn_s_setprio(0);

    if (t < NT - 1) {
      asm volatile("s_waitcnt vmcnt(0)" ::: "memory");  // next tile landed
      __builtin_amdgcn_sched_barrier(0);
      __builtin_amdgcn_s_barrier();
    }
  }

  // ---- epilogue: per-sample sum |out|^2 for this nb (group-uniform) ----
#pragma unroll
  for (int fm = 0; fm < 8; ++fm) {
    float sn[4] = {0, 0, 0, 0};
#pragma unroll
    for (int fn = 0; fn < 2; ++fn) {
#pragma unroll
      for (int r = 0; r < 4; ++r) {
        const float vv = acc[fm][fn][r];
        sn[r] = fmaf(vv, vv, sn[r]);
      }
    }
#pragma unroll
    for (int off = 1; off < 16; off <<= 1) {
#pragma unroll
      for (int r = 0; r < 4; ++r) sn[r] += __shfl_xor(sn[r], off);
    }
    if ((lane & 15) == 0) {
#pragma unroll
      for (int r = 0; r < 4; ++r) {
        const int m = m0 + wm * 128 + fm * 16 + (lane >> 4) * 4 + r;
        accb[(size_t)nb * BATCH + m] = sn[r];
      }
    }
  }
}

// ---------------------------------------------------------------------------
// K4/K5: per-sample loss + mean reduction. S scaled by 1/(32*16)^2.
// Groups: A = nb 0-3, B = nb 4-7, C = nb 8-11.
// ---------------------------------------------------------------------------
__global__ __launch_bounds__(256) void loss_partial(const float* __restrict__ accb,
                                                    const float* __restrict__ xn2,
                                                    const int* __restrict__ y,
                                                    float* __restrict__ partial) {
  const int s = blockIdx.x * 256 + threadIdx.x;
  float SA = 0.0f, SB = 0.0f, SC = 0.0f;
#pragma unroll
  for (int k = 0; k < 4; ++k) {
    SA += accb[(size_t)(0 + k) * BATCH + s];
    SB += accb[(size_t)(4 + k) * BATCH + s];
    SC += accb[(size_t)(8 + k) * BATCH + s];
  }
  SA *= SINV; SB *= SINV; SC *= SINV;
  const float n2 = xn2[s];
  const float z0 = n2 - 2.0f * (SA + SC);
  const float z1 = n2 - 2.0f * (SB + SC);
  const float inv = 1.0f / n2;
  const float l0 = z0 * inv, l1 = z1 * inv;
  const float mx = fmaxf(l0, l1);
  const float lse = mx + logf(expf(l0 - mx) + expf(l1 - mx));
  float loss = lse - ((y[s] == 0) ? l0 : l1);

  __shared__ float sm[256];
  sm[threadIdx.x] = loss;
  __syncthreads();
  for (int st = 128; st > 0; st >>= 1) {
    if (threadIdx.x < st) sm[threadIdx.x] += sm[threadIdx.x + st];
    __syncthreads();
  }
  if (threadIdx.x == 0) partial[blockIdx.x] = sm[0];
}

__global__ __launch_bounds__(64) void loss_final(const float* __restrict__ partial,
                                                 float* __restrict__ out) {
  float v = partial[threadIdx.x];
#pragma unroll
  for (int off = 1; off < 64; off <<= 1) v += __shfl_xor(v, off);
  if (threadIdx.x == 0) out[0] = v * (1.0f / (float)BATCH);
}

// ---------------------------------------------------------------------------
extern "C" void kernel_launch(void* const* d_in, const int* in_sizes, int n_in,
                              void* d_out, int out_size, void* d_ws, size_t ws_size,
                              hipStream_t stream) {
  const float* x = (const float*)d_in[0];   // [16384, 784] f32
  const float* w = (const float*)d_in[1];   // [5, 10, 3] f32
  const int*   y = (const int*)d_in[2];     // [16384] i32

  char* ws = (char*)d_ws;
  char*     Xf8  = ws;                               // 16384*832 = 13.63 MB
  char*     W2Tu = ws + 13631488;                    // 1536*832 = 1.28 MB
  float*    xn2  = (float*)(ws + 14909440);          // 64 KB
  float*    accb = (float*)(ws + 14975232);          // 12*16384*4 = 768 KB
  float* partial = (float*)(ws + 15761408);          // 64 f32

  prep<<<2880, 256, 0, stream>>>(x, Xf8, xn2, w, W2Tu);
  gemm_fused<<<768, 512, 0, stream>>>(Xf8, W2Tu, accb);
  loss_partial<<<BATCH / 256, 256, 0, stream>>>(accb, xn2, y, partial);
  loss_final<<<1, 64, 0, stream>>>(partial, (float*)d_out);
}